// Round 5
// baseline (221.536 us; speedup 1.0000x reference)
//
#include <hip/hip_runtime.h>
#include <stdint.h>

#define S_LEN 4096
#define D_DIM 2048
#define NT 16
#define TD 128
#define KW 4
#define CTX 640
#define HID 256

typedef __bf16 bf16_t;
typedef __bf16 bf16x8 __attribute__((ext_vector_type(8)));
typedef __bf16 bf16x4 __attribute__((ext_vector_type(4)));
typedef float f32x4 __attribute__((ext_vector_type(4)));
typedef unsigned int u32;
typedef u32 __attribute__((address_space(1))) gu32;
typedef u32 __attribute__((address_space(3))) lu32;

__device__ __forceinline__ void gload_lds16(const void* g, void* l) {
    __builtin_amdgcn_global_load_lds((const gu32*)g, (lu32*)l, 16, 0, 0);
}

// ---------------- Kernel 1: LayerNorm + x_norm(bf16) + per-block tile-sum partials
// 512 blocks x 16 rows each (4 rows/wave). partial: [512][2048] f32.
__global__ __launch_bounds__(256) void k_ln(const float* __restrict__ x,
        const float* __restrict__ gamma, const float* __restrict__ beta,
        bf16_t* __restrict__ xn, float* __restrict__ partial)
{
    __shared__ float wsum[4][2048];
    const int tid = threadIdx.x, lane = tid & 63, w = tid >> 6;
    const int blk = blockIdx.x;
    float cs[8][4];
#pragma unroll
    for (int j = 0; j < 8; ++j) { cs[j][0]=0.f; cs[j][1]=0.f; cs[j][2]=0.f; cs[j][3]=0.f; }
#pragma unroll
    for (int i = 0; i < 4; ++i) {
        const int r = blk*16 + w*4 + i;
        const float4* xr = (const float4*)(x + (size_t)r * D_DIM);
        float4 v[8]; float s = 0.f, ss = 0.f;
#pragma unroll
        for (int j = 0; j < 8; ++j) {
            v[j] = xr[j*64 + lane];
            s  += v[j].x + v[j].y + v[j].z + v[j].w;
            ss += v[j].x*v[j].x + v[j].y*v[j].y + v[j].z*v[j].z + v[j].w*v[j].w;
        }
#pragma unroll
        for (int off = 32; off; off >>= 1) { s += __shfl_xor(s, off); ss += __shfl_xor(ss, off); }
        const float mean = s * (1.f/2048.f);
        const float var  = ss * (1.f/2048.f) - mean*mean;
        const float rstd = rsqrtf(var + 1e-5f);
#pragma unroll
        for (int j = 0; j < 8; ++j) {
            const int c4 = j*64 + lane;
            const float4 g4 = *(const float4*)(gamma + c4*4);
            const float4 b4 = *(const float4*)(beta  + c4*4);
            float n0 = (v[j].x - mean)*rstd*g4.x + b4.x;
            float n1 = (v[j].y - mean)*rstd*g4.y + b4.y;
            float n2 = (v[j].z - mean)*rstd*g4.z + b4.z;
            float n3 = (v[j].w - mean)*rstd*g4.w + b4.w;
            cs[j][0]+=n0; cs[j][1]+=n1; cs[j][2]+=n2; cs[j][3]+=n3;
            bf16x4 o; o[0]=(bf16_t)n0; o[1]=(bf16_t)n1; o[2]=(bf16_t)n2; o[3]=(bf16_t)n3;
            *(bf16x4*)(xn + (size_t)r*D_DIM + c4*4) = o;
        }
    }
#pragma unroll
    for (int j = 0; j < 8; ++j) {
        float4 t4; t4.x=cs[j][0]; t4.y=cs[j][1]; t4.z=cs[j][2]; t4.w=cs[j][3];
        *(float4*)&wsum[w][(j*64+lane)*4] = t4;
    }
    __syncthreads();
#pragma unroll
    for (int p = 0; p < 2; ++p) {
        const int c4 = p*256 + tid;  // 0..511 (float4 index)
        float4 a0 = *(const float4*)&wsum[0][c4*4];
        float4 a1 = *(const float4*)&wsum[1][c4*4];
        float4 a2 = *(const float4*)&wsum[2][c4*4];
        float4 a3 = *(const float4*)&wsum[3][c4*4];
        float4 r4; r4.x=a0.x+a1.x+a2.x+a3.x; r4.y=a0.y+a1.y+a2.y+a3.y;
        r4.z=a0.z+a1.z+a2.z+a3.z; r4.w=a0.w+a1.w+a2.w+a3.w;
        *(float4*)(partial + (size_t)blk*D_DIM + c4*4) = r4;
    }
}

// ---------------- Kernel 2a: partial[512][2048] -> partial2[64][2048]
__global__ __launch_bounds__(256) void k_red1(const float* __restrict__ partial,
                                              float* __restrict__ partial2) {
    const int g = blockIdx.x, tid = threadIdx.x;   // 64 blocks
#pragma unroll
    for (int p = 0; p < 2; ++p) {
        const int c4 = p*256 + tid;
        float4 s = {0.f,0.f,0.f,0.f};
#pragma unroll
        for (int r = 0; r < 8; ++r) {
            float4 v = *(const float4*)(partial + ((size_t)(g*8+r))*2048 + c4*4);
            s.x+=v.x; s.y+=v.y; s.z+=v.z; s.w+=v.w;
        }
        *(float4*)(partial2 + (size_t)g*2048 + c4*4) = s;
    }
}

// ---------------- Kernel 3a: reduce partial2 + q/k projection + l2norm
// -> qkbuf[2(which)][2][16][128].  64 blocks: one per (b, t, which).
__global__ __launch_bounds__(256) void k_qk(const float* __restrict__ partial2,
        const float* __restrict__ Wq, const float* __restrict__ bq,
        const float* __restrict__ Wk, const float* __restrict__ bk,
        float* __restrict__ qkbuf)
{
    __shared__ float red2[2][128];
    __shared__ float rrow[128];
    __shared__ float yrow[128];
    __shared__ float ssum[2];
    const int g = blockIdx.x;
    const int b = g >> 5, t = (g >> 1) & 15, which = g & 1;
    const float* W    = which ? Wk : Wq;
    const float* bias = which ? bk : bq;
    const int tid = threadIdx.x, lane = tid & 63, w = tid >> 6;
    // fold of old k_red2: rrow[c] = (sum over 32 partial2 rows)/4096
    {
        const int c = tid & 127, hh = tid >> 7;
        float s = 0.f;
#pragma unroll
        for (int r = 0; r < 16; ++r)
            s += partial2[(size_t)(b*32 + hh*16 + r)*2048 + t*128 + c];
        red2[hh][c] = s;
    }
    __syncthreads();
    if (tid < 128) rrow[tid] = (red2[0][tid] + red2[1][tid]) * (1.f/4096.f);
    __syncthreads();
    const int c0 = (lane & 15) * 8;
#pragma unroll
    for (int r = 0; r < 8; ++r) {
        const int d = r*16 + w*4 + (lane >> 4);   // covers 0..127
        const float4 w0 = *(const float4*)(W + d*128 + c0);
        const float4 w1 = *(const float4*)(W + d*128 + c0 + 4);
        float acc = w0.x*rrow[c0]   + w0.y*rrow[c0+1] + w0.z*rrow[c0+2] + w0.w*rrow[c0+3]
                  + w1.x*rrow[c0+4] + w1.y*rrow[c0+5] + w1.z*rrow[c0+6] + w1.w*rrow[c0+7];
#pragma unroll
        for (int off = 1; off <= 8; off <<= 1) acc += __shfl_xor(acc, off);
        if ((lane & 15) == 0) yrow[d] = acc + bias[d];
    }
    __syncthreads();
    if (tid < 128) {
        float v = yrow[tid];
        float sq = v * v;
#pragma unroll
        for (int off = 32; off; off >>= 1) sq += __shfl_xor(sq, off);
        if (lane == 0) ssum[tid >> 6] = sq;
    }
    __syncthreads();
    if (tid < 128) {
        const float rn = 1.f / fmaxf(sqrtf(ssum[0] + ssum[1]), 1e-12f);
        qkbuf[(which*32 + b*16 + t)*128 + tid] = yrow[tid] * rn;
    }
}

// ---------------- Kernel 3b: scores + top-4 -> routes [B][T][K]
__global__ __launch_bounds__(256) void k_score(const float* __restrict__ qkbuf,
                                               int* __restrict__ routes)
{
    __shared__ float qk_s[8192];      // [which(2)][b(2)][t(16)][128]
    __shared__ float sc[2][16][16];
    const int tid = threadIdx.x;
    for (int i = tid; i < 2048; i += 256)
        *(float4*)&qk_s[i*4] = *(const float4*)(qkbuf + i*4);
    __syncthreads();
#pragma unroll
    for (int p = 0; p < 2; ++p) {
        const int e = p*256 + tid;            // 0..511
        const int b = e >> 8, t = (e >> 4) & 15, u = e & 15;
        const float4* qr = (const float4*)&qk_s[(b*16 + t)*128];
        const float4* kr = (const float4*)&qk_s[(32 + b*16 + u)*128];
        float s = 0.f;
#pragma unroll
        for (int c = 0; c < 32; ++c) {
            float4 a = qr[c], bb = kr[c];
            s += a.x*bb.x + a.y*bb.y + a.z*bb.z + a.w*bb.w;
        }
        sc[b][t][u] = (u == t) ? -1e9f : s;
    }
    __syncthreads();
    if (tid < 32) {
        const int b = tid >> 4, t = tid & 15;
        unsigned taken = 0;
        for (int kk = 0; kk < 4; ++kk) {
            float bv = -3.0e38f; int bu = 0;
            for (int u = 0; u < 16; ++u) {
                if ((taken >> u) & 1u) continue;
                const float v = sc[b][t][u];
                if (v > bv) { bv = v; bu = u; }   // strict > = lax.top_k tie-break
            }
            taken |= (1u << bu);
            routes[(b*16 + t)*4 + kk] = bu;
        }
    }
}

// ---------------- Kernel 4: pre-tile + pre-swizzle W1/W2 into bf16 LDS images
// LDS slot L holds logical element at (byte L) ^ ((row&7)<<4)  [rows of 128B]
__global__ void k_prep(const float* __restrict__ W1, const float* __restrict__ W2,
                       bf16_t* __restrict__ W1t, bf16_t* __restrict__ W2t) {
    const int g = blockIdx.x * 256 + threadIdx.x;
    if (g < 10*256*64) {
        const int ks = g >> 14, rem = g & 16383, n = rem >> 6, kk = rem & 63;
        const int kkl = ((kk << 1) ^ ((n & 7) << 4)) >> 1;
        W1t[g] = (bf16_t)W1[n*CTX + ks*64 + kkl];
    } else if (g < 10*256*64 + 4*128*64) {
        const int gg = g - 10*256*64;
        const int ks = gg >> 13, rem = gg & 8191, n = rem >> 6, kk = rem & 63;
        const int kkl = ((kk << 1) ^ ((n & 7) << 4)) >> 1;
        W2t[gg] = (bf16_t)W2[n*HID + ks*64 + kkl];
    }
}

// ---------------- Kernel 5: fused gather + MLP (2 GEMMs, bf16 MFMA) + residual
// BM=128 rows (8 s x 16 t), 4 waves, N1=256 split 64/wave, N2=128 split 32/wave.
// LDS 48.5KB -> 3 blocks/CU: combL @0 (16K), w1L @16K (32K);
// GEMM2: hL @0 (32K, aliases dead combL+w1L-lower), w2L @32K (16K, aliases
// dead w1L-upper), srcT @48K. Every alias transition is barrier-separated.
__global__ __launch_bounds__(256, 3) void k_mlp(
    const float* __restrict__ x, const bf16_t* __restrict__ xn,
    const bf16_t* __restrict__ W1t, const bf16_t* __restrict__ W2t,
    const float* __restrict__ b1, const float* __restrict__ b2,
    const int* __restrict__ routes, float* __restrict__ out)
{
    __shared__ char lds[49664];
    char* combL = lds;                  // [128][64] bf16, 16KB   (GEMM1)
    char* w1L   = lds + 16384;          // [256][64] bf16, 32KB   (GEMM1)
    char* hL    = lds;                  // [128][128] bf16, 32KB  (GEMM2, phased)
    char* w2L   = lds + 32768;          // [128][64] bf16, 16KB   (GEMM2)
    int*  srcT  = (int*)(lds + 49152);  // [16][5]

    const int tid = threadIdx.x, lane = tid & 63, w = tid >> 6;
    const int blk = blockIdx.x;
    const int b  = blk >> 9;
    const int s0 = (blk & 511) * 8;

    if (tid < 80) {
        const int t = tid / 5, j = tid % 5;
        srcT[tid] = (j == 0) ? t : routes[(b*NT + t)*KW + (j-1)];
    }
    __syncthreads();

    // staging-lane constants: chunk q=it*4+w covers m = it*32 + w*8 + (lane>>3)
    const int sub = w*8 + (lane >> 3);          // 0..31
    const int tt  = sub & 15;                   // tile index t of this lane's m-rows
    const int hi  = sub >> 4;                   // 0/1
    const size_t rowc = ((size_t)(b*S_LEN + s0 + hi)) * D_DIM;
    const int kkE = ((lane & 7) ^ ((lane >> 3) & 7)) * 8;  // source-side swizzle

    f32x4 acc[4][8];
#pragma unroll
    for (int i = 0; i < 4; ++i)
#pragma unroll
        for (int j = 0; j < 8; ++j) acc[i][j] = (f32x4){0.f,0.f,0.f,0.f};

    const int nbase = w * 64;

    for (int ks = 0; ks < 10; ++ks) {
        const int src = srcT[tt*5 + (ks >> 1)];
        const size_t cbase = rowc + (size_t)src*TD + (size_t)((ks & 1)*64 + kkE);
#pragma unroll
        for (int it = 0; it < 4; ++it)
            gload_lds16(xn + cbase + (size_t)it*2*D_DIM, combL + (it*4 + w)*1024);
        const bf16_t* w1g = W1t + ks*16384 + lane*8;
#pragma unroll
        for (int it = 0; it < 8; ++it) {
            const int q = it*4 + w;
            gload_lds16(w1g + q*512, w1L + q*1024);
        }
        asm volatile("s_waitcnt vmcnt(0)");
        __syncthreads();
#pragma unroll
        for (int kk = 0; kk < 2; ++kk) {
            const int kb = (kk*32 + ((lane >> 4) * 8)) * 2;
            bf16x8 af[4], bfr[8];
#pragma unroll
            for (int nf = 0; nf < 4; ++nf) {
                const int n = nbase + nf*16 + (lane & 15);
                af[nf] = *(const bf16x8*)(w1L + n*128 + (kb ^ ((n & 7) << 4)));
            }
#pragma unroll
            for (int mf = 0; mf < 8; ++mf) {
                const int m = mf*16 + (lane & 15);
                bfr[mf] = *(const bf16x8*)(combL + m*128 + (kb ^ ((m & 7) << 4)));
            }
#pragma unroll
            for (int nf = 0; nf < 4; ++nf)
#pragma unroll
                for (int mf = 0; mf < 8; ++mf)
                    acc[nf][mf] = __builtin_amdgcn_mfma_f32_16x16x32_bf16(
                        af[nf], bfr[mf], acc[nf][mf], 0, 0, 0);
        }
        __syncthreads();
    }

    // epilogue 1: bias + gelu (tanh approx) -> packed bf16 regs
    bf16x4 hreg[4][8];
#pragma unroll
    for (int nf = 0; nf < 4; ++nf) {
        const int n0 = nbase + nf*16 + ((lane >> 4) * 4);
        const float4 b1v = *(const float4*)(b1 + n0);
#pragma unroll
        for (int mf = 0; mf < 8; ++mf) {
#pragma unroll
            for (int r = 0; r < 4; ++r) {
                const float z = acc[nf][mf][r] + ((const float*)&b1v)[r];
                const float u = z + 0.044715f * z * z * z;
                const float gl = z / (1.f + __expf(-1.5957691216f * u));
                hreg[nf][mf][r] = (bf16_t)gl;
            }
        }
    }

    // phase A: waves 0,1 write h columns 0..127 into hL
    const int colb = (nbase & 127) + ((lane >> 4) * 4);
    if (w < 2) {
#pragma unroll
        for (int nf = 0; nf < 4; ++nf) {
            const int cb2 = (colb + nf*16) * 2;
#pragma unroll
            for (int mf = 0; mf < 8; ++mf) {
                const int m = mf*16 + (lane & 15);
                *(bf16x4*)(hL + m*256 + (cb2 ^ ((m & 7) << 4))) = hreg[nf][mf];
            }
        }
    }

    // GEMM2: out = h @ W2^T, K=256 in two phases of 128
    f32x4 acc2[2][8];
#pragma unroll
    for (int i = 0; i < 2; ++i)
#pragma unroll
        for (int j = 0; j < 8; ++j) acc2[i][j] = (f32x4){0.f,0.f,0.f,0.f};

    for (int ks2 = 0; ks2 < 4; ++ks2) {
        if (ks2 == 2) {
            if (w >= 2) {   // phase B: waves 2,3 write h columns 128..255
#pragma unroll
                for (int nf = 0; nf < 4; ++nf) {
                    const int cb2 = (colb + nf*16) * 2;
#pragma unroll
                    for (int mf = 0; mf < 8; ++mf) {
                        const int m = mf*16 + (lane & 15);
                        *(bf16x4*)(hL + m*256 + (cb2 ^ ((m & 7) << 4))) = hreg[nf][mf];
                    }
                }
            }
            __syncthreads();
        }
        const bf16_t* w2g = W2t + ks2*8192 + lane*8;
#pragma unroll
        for (int it = 0; it < 4; ++it) {
            const int q = it*4 + w;
            gload_lds16(w2g + q*512, w2L + q*1024);
        }
        asm volatile("s_waitcnt vmcnt(0)");
        __syncthreads();
#pragma unroll
        for (int kk = 0; kk < 2; ++kk) {
            const int kbW = (kk*32 + ((lane >> 4) * 8)) * 2;
            const int kbH = (((ks2 & 1) * 64) + kk*32 + ((lane >> 4) * 8)) * 2;
            bf16x8 ah[8], bw2[2];
#pragma unroll
            for (int mf = 0; mf < 8; ++mf) {
                const int m = mf*16 + (lane & 15);
                ah[mf] = *(const bf16x8*)(hL + m*256 + (kbH ^ ((m & 7) << 4)));
            }
#pragma unroll
            for (int nf = 0; nf < 2; ++nf) {
                const int n2 = w*32 + nf*16 + (lane & 15);
                bw2[nf] = *(const bf16x8*)(w2L + n2*128 + (kbW ^ ((n2 & 7) << 4)));
            }
#pragma unroll
            for (int nf = 0; nf < 2; ++nf)
#pragma unroll
                for (int mf = 0; mf < 8; ++mf)
                    acc2[nf][mf] = __builtin_amdgcn_mfma_f32_16x16x32_bf16(
                        ah[mf], bw2[nf], acc2[nf][mf], 0, 0, 0);
        }
        __syncthreads();
    }

    // epilogue 2: + b2 + residual x
#pragma unroll
    for (int nf = 0; nf < 2; ++nf) {
        const int n2 = w*32 + nf*16 + (lane & 15);
        const float b2v = b2[n2];
#pragma unroll
        for (int mf = 0; mf < 8; ++mf) {
            const int mb = mf*16 + ((lane >> 4) * 4);
#pragma unroll
            for (int r = 0; r < 4; ++r) {
                const int m = mb + r;
                const int s = s0 + (m >> 4);
                const int t = m & 15;
                const size_t o = ((size_t)(b*S_LEN + s))*D_DIM + t*TD + n2;
                out[o] = x[o] + acc2[nf][mf][r] + b2v;
            }
        }
    }
}

extern "C" void kernel_launch(void* const* d_in, const int* in_sizes, int n_in,
                              void* d_out, int out_size, void* d_ws, size_t ws_size,
                              hipStream_t stream) {
    const float* x     = (const float*)d_in[0];
    const float* gamma = (const float*)d_in[1];
    const float* beta  = (const float*)d_in[2];
    const float* Wq    = (const float*)d_in[3];
    const float* bq    = (const float*)d_in[4];
    const float* Wk    = (const float*)d_in[5];
    const float* bk    = (const float*)d_in[6];
    const float* W1    = (const float*)d_in[7];
    const float* b1    = (const float*)d_in[8];
    const float* W2    = (const float*)d_in[9];
    const float* b2    = (const float*)d_in[10];
    float* out = (float*)d_out;

    char* ws = (char*)d_ws;
    bf16_t* xn       = (bf16_t*)ws;                   // 33,554,432 B
    float*  partial  = (float*) (ws + 33554432);      //  4,194,304 B [512][2048]
    float*  partial2 = (float*) (ws + 37748736);      //    524,288 B [64][2048]
    float*  qkbuf    = (float*) (ws + 38273024);      //     32,768 B
    int*    routes   = (int*)   (ws + 38305792);      //        512 B
    bf16_t* W1t      = (bf16_t*)(ws + 38306304);      //    327,680 B
    bf16_t* W2t      = (bf16_t*)(ws + 38633984);      //     65,536 B

    k_prep<<<768, 256, 0, stream>>>(W1, W2, W1t, W2t);
    k_ln<<<512, 256, 0, stream>>>(x, gamma, beta, xn, partial);
    k_red1<<<64, 256, 0, stream>>>(partial, partial2);
    k_qk<<<64, 256, 0, stream>>>(partial2, Wq, bq, Wk, bk, qkbuf);
    k_score<<<1, 256, 0, stream>>>(qkbuf, routes);
    k_mlp<<<1024, 256, 0, stream>>>(x, xn, W1t, W2t, b1, b2, routes, out);
}

// Round 6
// 127.620 us; speedup vs baseline: 1.7359x; 1.7359x over previous
//
#include <hip/hip_runtime.h>
#include <stdint.h>

#define S_LEN 4096
#define D_DIM 2048
#define NT 16
#define TD 128
#define KW 4
#define CTX 640
#define HID 256

typedef __bf16 bf16_t;
typedef __bf16 bf16x8 __attribute__((ext_vector_type(8)));
typedef __bf16 bf16x4 __attribute__((ext_vector_type(4)));
typedef float f32x4 __attribute__((ext_vector_type(4)));
typedef unsigned int u32;
typedef u32 __attribute__((address_space(1))) gu32;
typedef u32 __attribute__((address_space(3))) lu32;

__device__ __forceinline__ void gload_lds16(const void* g, void* l) {
    __builtin_amdgcn_global_load_lds((const gu32*)g, (lu32*)l, 16, 0, 0);
}

// ---------------- Kernel 1: LayerNorm + x_norm(bf16) + per-block tile-sum partials
// 512 blocks x 16 rows each (4 rows/wave). partial: [512][2048] f32.
__global__ __launch_bounds__(256) void k_ln(const float* __restrict__ x,
        const float* __restrict__ gamma, const float* __restrict__ beta,
        bf16_t* __restrict__ xn, float* __restrict__ partial)
{
    __shared__ float wsum[4][2048];
    const int tid = threadIdx.x, lane = tid & 63, w = tid >> 6;
    const int blk = blockIdx.x;
    float cs[8][4];
#pragma unroll
    for (int j = 0; j < 8; ++j) { cs[j][0]=0.f; cs[j][1]=0.f; cs[j][2]=0.f; cs[j][3]=0.f; }
#pragma unroll
    for (int i = 0; i < 4; ++i) {
        const int r = blk*16 + w*4 + i;
        const float4* xr = (const float4*)(x + (size_t)r * D_DIM);
        float4 v[8]; float s = 0.f, ss = 0.f;
#pragma unroll
        for (int j = 0; j < 8; ++j) {
            v[j] = xr[j*64 + lane];
            s  += v[j].x + v[j].y + v[j].z + v[j].w;
            ss += v[j].x*v[j].x + v[j].y*v[j].y + v[j].z*v[j].z + v[j].w*v[j].w;
        }
#pragma unroll
        for (int off = 32; off; off >>= 1) { s += __shfl_xor(s, off); ss += __shfl_xor(ss, off); }
        const float mean = s * (1.f/2048.f);
        const float var  = ss * (1.f/2048.f) - mean*mean;
        const float rstd = rsqrtf(var + 1e-5f);
#pragma unroll
        for (int j = 0; j < 8; ++j) {
            const int c4 = j*64 + lane;
            const float4 g4 = *(const float4*)(gamma + c4*4);
            const float4 b4 = *(const float4*)(beta  + c4*4);
            float n0 = (v[j].x - mean)*rstd*g4.x + b4.x;
            float n1 = (v[j].y - mean)*rstd*g4.y + b4.y;
            float n2 = (v[j].z - mean)*rstd*g4.z + b4.z;
            float n3 = (v[j].w - mean)*rstd*g4.w + b4.w;
            cs[j][0]+=n0; cs[j][1]+=n1; cs[j][2]+=n2; cs[j][3]+=n3;
            bf16x4 o; o[0]=(bf16_t)n0; o[1]=(bf16_t)n1; o[2]=(bf16_t)n2; o[3]=(bf16_t)n3;
            *(bf16x4*)(xn + (size_t)r*D_DIM + c4*4) = o;
        }
    }
#pragma unroll
    for (int j = 0; j < 8; ++j) {
        float4 t4; t4.x=cs[j][0]; t4.y=cs[j][1]; t4.z=cs[j][2]; t4.w=cs[j][3];
        *(float4*)&wsum[w][(j*64+lane)*4] = t4;
    }
    __syncthreads();
#pragma unroll
    for (int p = 0; p < 2; ++p) {
        const int c4 = p*256 + tid;  // 0..511 (float4 index)
        float4 a0 = *(const float4*)&wsum[0][c4*4];
        float4 a1 = *(const float4*)&wsum[1][c4*4];
        float4 a2 = *(const float4*)&wsum[2][c4*4];
        float4 a3 = *(const float4*)&wsum[3][c4*4];
        float4 r4; r4.x=a0.x+a1.x+a2.x+a3.x; r4.y=a0.y+a1.y+a2.y+a3.y;
        r4.z=a0.z+a1.z+a2.z+a3.z; r4.w=a0.w+a1.w+a2.w+a3.w;
        *(float4*)(partial + (size_t)blk*D_DIM + c4*4) = r4;
    }
}

// ---------------- Kernel 2a: partial[512][2048] -> partial2[64][2048]
__global__ __launch_bounds__(256) void k_red1(const float* __restrict__ partial,
                                              float* __restrict__ partial2) {
    const int g = blockIdx.x, tid = threadIdx.x;   // 64 blocks
#pragma unroll
    for (int p = 0; p < 2; ++p) {
        const int c4 = p*256 + tid;
        float4 s = {0.f,0.f,0.f,0.f};
#pragma unroll
        for (int r = 0; r < 8; ++r) {
            float4 v = *(const float4*)(partial + ((size_t)(g*8+r))*2048 + c4*4);
            s.x+=v.x; s.y+=v.y; s.z+=v.z; s.w+=v.w;
        }
        *(float4*)(partial2 + (size_t)g*2048 + c4*4) = s;
    }
}

// ---------------- Kernel 3a: reduce partial2 + q/k projection + l2norm
// -> qkbuf[2(which)][2][16][128].  64 blocks: one per (b, t, which).
__global__ __launch_bounds__(256) void k_qk(const float* __restrict__ partial2,
        const float* __restrict__ Wq, const float* __restrict__ bq,
        const float* __restrict__ Wk, const float* __restrict__ bk,
        float* __restrict__ qkbuf)
{
    __shared__ float red2[2][128];
    __shared__ float rrow[128];
    __shared__ float yrow[128];
    __shared__ float ssum[2];
    const int g = blockIdx.x;
    const int b = g >> 5, t = (g >> 1) & 15, which = g & 1;
    const float* W    = which ? Wk : Wq;
    const float* bias = which ? bk : bq;
    const int tid = threadIdx.x, lane = tid & 63, w = tid >> 6;
    // fold of old k_red2: rrow[c] = (sum over 32 partial2 rows)/4096
    {
        const int c = tid & 127, hh = tid >> 7;
        float s = 0.f;
#pragma unroll
        for (int r = 0; r < 16; ++r)
            s += partial2[(size_t)(b*32 + hh*16 + r)*2048 + t*128 + c];
        red2[hh][c] = s;
    }
    __syncthreads();
    if (tid < 128) rrow[tid] = (red2[0][tid] + red2[1][tid]) * (1.f/4096.f);
    __syncthreads();
    const int c0 = (lane & 15) * 8;
#pragma unroll
    for (int r = 0; r < 8; ++r) {
        const int d = r*16 + w*4 + (lane >> 4);   // covers 0..127
        const float4 w0 = *(const float4*)(W + d*128 + c0);
        const float4 w1 = *(const float4*)(W + d*128 + c0 + 4);
        float acc = w0.x*rrow[c0]   + w0.y*rrow[c0+1] + w0.z*rrow[c0+2] + w0.w*rrow[c0+3]
                  + w1.x*rrow[c0+4] + w1.y*rrow[c0+5] + w1.z*rrow[c0+6] + w1.w*rrow[c0+7];
#pragma unroll
        for (int off = 1; off <= 8; off <<= 1) acc += __shfl_xor(acc, off);
        if ((lane & 15) == 0) yrow[d] = acc + bias[d];
    }
    __syncthreads();
    if (tid < 128) {
        float v = yrow[tid];
        float sq = v * v;
#pragma unroll
        for (int off = 32; off; off >>= 1) sq += __shfl_xor(sq, off);
        if (lane == 0) ssum[tid >> 6] = sq;
    }
    __syncthreads();
    if (tid < 128) {
        const float rn = 1.f / fmaxf(sqrtf(ssum[0] + ssum[1]), 1e-12f);
        qkbuf[(which*32 + b*16 + t)*128 + tid] = yrow[tid] * rn;
    }
}

// ---------------- Kernel 3b: scores + top-4 -> routes [B][T][K]
__global__ __launch_bounds__(256) void k_score(const float* __restrict__ qkbuf,
                                               int* __restrict__ routes)
{
    __shared__ float qk_s[8192];      // [which(2)][b(2)][t(16)][128]
    __shared__ float sc[2][16][16];
    const int tid = threadIdx.x;
    for (int i = tid; i < 2048; i += 256)
        *(float4*)&qk_s[i*4] = *(const float4*)(qkbuf + i*4);
    __syncthreads();
#pragma unroll
    for (int p = 0; p < 2; ++p) {
        const int e = p*256 + tid;            // 0..511
        const int b = e >> 8, t = (e >> 4) & 15, u = e & 15;
        const float4* qr = (const float4*)&qk_s[(b*16 + t)*128];
        const float4* kr = (const float4*)&qk_s[(32 + b*16 + u)*128];
        float s = 0.f;
#pragma unroll
        for (int c = 0; c < 32; ++c) {
            float4 a = qr[c], bb = kr[c];
            s += a.x*bb.x + a.y*bb.y + a.z*bb.z + a.w*bb.w;
        }
        sc[b][t][u] = (u == t) ? -1e9f : s;
    }
    __syncthreads();
    if (tid < 32) {
        const int b = tid >> 4, t = tid & 15;
        unsigned taken = 0;
        for (int kk = 0; kk < 4; ++kk) {
            float bv = -3.0e38f; int bu = 0;
            for (int u = 0; u < 16; ++u) {
                if ((taken >> u) & 1u) continue;
                const float v = sc[b][t][u];
                if (v > bv) { bv = v; bu = u; }   // strict > = lax.top_k tie-break
            }
            taken |= (1u << bu);
            routes[(b*16 + t)*4 + kk] = bu;
        }
    }
}

// ---------------- Kernel 4: pre-tile + pre-swizzle W1/W2 into bf16 LDS images
// LDS slot L holds logical element at (byte L) ^ ((row&7)<<4)  [rows of 128B]
__global__ void k_prep(const float* __restrict__ W1, const float* __restrict__ W2,
                       bf16_t* __restrict__ W1t, bf16_t* __restrict__ W2t) {
    const int g = blockIdx.x * 256 + threadIdx.x;
    if (g < 10*256*64) {
        const int ks = g >> 14, rem = g & 16383, n = rem >> 6, kk = rem & 63;
        const int kkl = ((kk << 1) ^ ((n & 7) << 4)) >> 1;
        W1t[g] = (bf16_t)W1[n*CTX + ks*64 + kkl];
    } else if (g < 10*256*64 + 4*128*64) {
        const int gg = g - 10*256*64;
        const int ks = gg >> 13, rem = gg & 8191, n = rem >> 6, kk = rem & 63;
        const int kkl = ((kk << 1) ^ ((n & 7) << 4)) >> 1;
        W2t[gg] = (bf16_t)W2[n*HID + ks*64 + kkl];
    }
}

// ---------------- Kernel 5: fused gather + MLP (2 GEMMs, bf16 MFMA) + residual
// BM=128 rows (8 s x 16 t), 4 waves, N1=256 split 64/wave, N2=128 split 32/wave.
// LDS 48.5KB -> 3 blocks/CU (LDS-limited): combL @0 (16K), w1L @16K (32K);
// GEMM2: hL @0 (32K, aliases dead combL+w1L-lower), w2L @32K (16K, aliases
// dead w1L-upper), srcT @48K. Every alias transition is barrier-separated.
// NOTE: launch_bounds min-waves stays at 2 — declaring 3 caps VGPR at 84 and
// spills the 128-reg accumulator to scratch (round-5 regression: 206us,
// WRITE_SIZE 388MB). VGPR=112 fits 4 waves/SIMD; LDS picks occupancy=3.
__global__ __launch_bounds__(256, 2) void k_mlp(
    const float* __restrict__ x, const bf16_t* __restrict__ xn,
    const bf16_t* __restrict__ W1t, const bf16_t* __restrict__ W2t,
    const float* __restrict__ b1, const float* __restrict__ b2,
    const int* __restrict__ routes, float* __restrict__ out)
{
    __shared__ char lds[49664];
    char* combL = lds;                  // [128][64] bf16, 16KB   (GEMM1)
    char* w1L   = lds + 16384;          // [256][64] bf16, 32KB   (GEMM1)
    char* hL    = lds;                  // [128][128] bf16, 32KB  (GEMM2, phased)
    char* w2L   = lds + 32768;          // [128][64] bf16, 16KB   (GEMM2)
    int*  srcT  = (int*)(lds + 49152);  // [16][5]

    const int tid = threadIdx.x, lane = tid & 63, w = tid >> 6;
    const int blk = blockIdx.x;
    const int b  = blk >> 9;
    const int s0 = (blk & 511) * 8;

    if (tid < 80) {
        const int t = tid / 5, j = tid % 5;
        srcT[tid] = (j == 0) ? t : routes[(b*NT + t)*KW + (j-1)];
    }
    __syncthreads();

    // staging-lane constants: chunk q=it*4+w covers m = it*32 + w*8 + (lane>>3)
    const int sub = w*8 + (lane >> 3);          // 0..31
    const int tt  = sub & 15;                   // tile index t of this lane's m-rows
    const int hi  = sub >> 4;                   // 0/1
    const size_t rowc = ((size_t)(b*S_LEN + s0 + hi)) * D_DIM;
    const int kkE = ((lane & 7) ^ ((lane >> 3) & 7)) * 8;  // source-side swizzle

    f32x4 acc[4][8];
#pragma unroll
    for (int i = 0; i < 4; ++i)
#pragma unroll
        for (int j = 0; j < 8; ++j) acc[i][j] = (f32x4){0.f,0.f,0.f,0.f};

    const int nbase = w * 64;

    for (int ks = 0; ks < 10; ++ks) {
        const int src = srcT[tt*5 + (ks >> 1)];
        const size_t cbase = rowc + (size_t)src*TD + (size_t)((ks & 1)*64 + kkE);
#pragma unroll
        for (int it = 0; it < 4; ++it)
            gload_lds16(xn + cbase + (size_t)it*2*D_DIM, combL + (it*4 + w)*1024);
        const bf16_t* w1g = W1t + ks*16384 + lane*8;
#pragma unroll
        for (int it = 0; it < 8; ++it) {
            const int q = it*4 + w;
            gload_lds16(w1g + q*512, w1L + q*1024);
        }
        asm volatile("s_waitcnt vmcnt(0)");
        __syncthreads();
#pragma unroll
        for (int kk = 0; kk < 2; ++kk) {
            const int kb = (kk*32 + ((lane >> 4) * 8)) * 2;
            bf16x8 af[4], bfr[8];
#pragma unroll
            for (int nf = 0; nf < 4; ++nf) {
                const int n = nbase + nf*16 + (lane & 15);
                af[nf] = *(const bf16x8*)(w1L + n*128 + (kb ^ ((n & 7) << 4)));
            }
#pragma unroll
            for (int mf = 0; mf < 8; ++mf) {
                const int m = mf*16 + (lane & 15);
                bfr[mf] = *(const bf16x8*)(combL + m*128 + (kb ^ ((m & 7) << 4)));
            }
#pragma unroll
            for (int nf = 0; nf < 4; ++nf)
#pragma unroll
                for (int mf = 0; mf < 8; ++mf)
                    acc[nf][mf] = __builtin_amdgcn_mfma_f32_16x16x32_bf16(
                        af[nf], bfr[mf], acc[nf][mf], 0, 0, 0);
        }
        __syncthreads();
    }

    // epilogue 1: bias + gelu (tanh approx) -> packed bf16 regs
    bf16x4 hreg[4][8];
#pragma unroll
    for (int nf = 0; nf < 4; ++nf) {
        const int n0 = nbase + nf*16 + ((lane >> 4) * 4);
        const float4 b1v = *(const float4*)(b1 + n0);
#pragma unroll
        for (int mf = 0; mf < 8; ++mf) {
#pragma unroll
            for (int r = 0; r < 4; ++r) {
                const float z = acc[nf][mf][r] + ((const float*)&b1v)[r];
                const float u = z + 0.044715f * z * z * z;
                const float gl = z / (1.f + __expf(-1.5957691216f * u));
                hreg[nf][mf][r] = (bf16_t)gl;
            }
        }
    }

    // phase A: waves 0,1 write h columns 0..127 into hL
    const int colb = (nbase & 127) + ((lane >> 4) * 4);
    if (w < 2) {
#pragma unroll
        for (int nf = 0; nf < 4; ++nf) {
            const int cb2 = (colb + nf*16) * 2;
#pragma unroll
            for (int mf = 0; mf < 8; ++mf) {
                const int m = mf*16 + (lane & 15);
                *(bf16x4*)(hL + m*256 + (cb2 ^ ((m & 7) << 4))) = hreg[nf][mf];
            }
        }
    }

    // GEMM2: out = h @ W2^T, K=256 in two phases of 128
    f32x4 acc2[2][8];
#pragma unroll
    for (int i = 0; i < 2; ++i)
#pragma unroll
        for (int j = 0; j < 8; ++j) acc2[i][j] = (f32x4){0.f,0.f,0.f,0.f};

    for (int ks2 = 0; ks2 < 4; ++ks2) {
        if (ks2 == 2) {
            if (w >= 2) {   // phase B: waves 2,3 write h columns 128..255
#pragma unroll
                for (int nf = 0; nf < 4; ++nf) {
                    const int cb2 = (colb + nf*16) * 2;
#pragma unroll
                    for (int mf = 0; mf < 8; ++mf) {
                        const int m = mf*16 + (lane & 15);
                        *(bf16x4*)(hL + m*256 + (cb2 ^ ((m & 7) << 4))) = hreg[nf][mf];
                    }
                }
            }
            __syncthreads();
        }
        const bf16_t* w2g = W2t + ks2*8192 + lane*8;
#pragma unroll
        for (int it = 0; it < 4; ++it) {
            const int q = it*4 + w;
            gload_lds16(w2g + q*512, w2L + q*1024);
        }
        asm volatile("s_waitcnt vmcnt(0)");
        __syncthreads();
#pragma unroll
        for (int kk = 0; kk < 2; ++kk) {
            const int kbW = (kk*32 + ((lane >> 4) * 8)) * 2;
            const int kbH = (((ks2 & 1) * 64) + kk*32 + ((lane >> 4) * 8)) * 2;
            bf16x8 ah[8], bw2[2];
#pragma unroll
            for (int mf = 0; mf < 8; ++mf) {
                const int m = mf*16 + (lane & 15);
                ah[mf] = *(const bf16x8*)(hL + m*256 + (kbH ^ ((m & 7) << 4)));
            }
#pragma unroll
            for (int nf = 0; nf < 2; ++nf) {
                const int n2 = w*32 + nf*16 + (lane & 15);
                bw2[nf] = *(const bf16x8*)(w2L + n2*128 + (kbW ^ ((n2 & 7) << 4)));
            }
#pragma unroll
            for (int nf = 0; nf < 2; ++nf)
#pragma unroll
                for (int mf = 0; mf < 8; ++mf)
                    acc2[nf][mf] = __builtin_amdgcn_mfma_f32_16x16x32_bf16(
                        ah[mf], bw2[nf], acc2[nf][mf], 0, 0, 0);
        }
        __syncthreads();
    }

    // epilogue 2: + b2 + residual x
#pragma unroll
    for (int nf = 0; nf < 2; ++nf) {
        const int n2 = w*32 + nf*16 + (lane & 15);
        const float b2v = b2[n2];
#pragma unroll
        for (int mf = 0; mf < 8; ++mf) {
            const int mb = mf*16 + ((lane >> 4) * 4);
#pragma unroll
            for (int r = 0; r < 4; ++r) {
                const int m = mb + r;
                const int s = s0 + (m >> 4);
                const int t = m & 15;
                const size_t o = ((size_t)(b*S_LEN + s))*D_DIM + t*TD + n2;
                out[o] = x[o] + acc2[nf][mf][r] + b2v;
            }
        }
    }
}

extern "C" void kernel_launch(void* const* d_in, const int* in_sizes, int n_in,
                              void* d_out, int out_size, void* d_ws, size_t ws_size,
                              hipStream_t stream) {
    const float* x     = (const float*)d_in[0];
    const float* gamma = (const float*)d_in[1];
    const float* beta  = (const float*)d_in[2];
    const float* Wq    = (const float*)d_in[3];
    const float* bq    = (const float*)d_in[4];
    const float* Wk    = (const float*)d_in[5];
    const float* bk    = (const float*)d_in[6];
    const float* W1    = (const float*)d_in[7];
    const float* b1    = (const float*)d_in[8];
    const float* W2    = (const float*)d_in[9];
    const float* b2    = (const float*)d_in[10];
    float* out = (float*)d_out;

    char* ws = (char*)d_ws;
    bf16_t* xn       = (bf16_t*)ws;                   // 33,554,432 B
    float*  partial  = (float*) (ws + 33554432);      //  4,194,304 B [512][2048]
    float*  partial2 = (float*) (ws + 37748736);      //    524,288 B [64][2048]
    float*  qkbuf    = (float*) (ws + 38273024);      //     32,768 B
    int*    routes   = (int*)   (ws + 38305792);      //        512 B
    bf16_t* W1t      = (bf16_t*)(ws + 38306304);      //    327,680 B
    bf16_t* W2t      = (bf16_t*)(ws + 38633984);      //     65,536 B

    k_prep<<<768, 256, 0, stream>>>(W1, W2, W1t, W2t);
    k_ln<<<512, 256, 0, stream>>>(x, gamma, beta, xn, partial);
    k_red1<<<64, 256, 0, stream>>>(partial, partial2);
    k_qk<<<64, 256, 0, stream>>>(partial2, Wq, bq, Wk, bk, qkbuf);
    k_score<<<1, 256, 0, stream>>>(qkbuf, routes);
    k_mlp<<<1024, 256, 0, stream>>>(x, xn, W1t, W2t, b1, b2, routes, out);
}

// Round 7
// 126.789 us; speedup vs baseline: 1.7473x; 1.0066x over previous
//
#include <hip/hip_runtime.h>
#include <stdint.h>

#define S_LEN 4096
#define D_DIM 2048
#define NT 16
#define TD 128
#define KW 4
#define CTX 640
#define HID 256

typedef __bf16 bf16_t;
typedef __bf16 bf16x8 __attribute__((ext_vector_type(8)));
typedef __bf16 bf16x4 __attribute__((ext_vector_type(4)));
typedef float f32x4 __attribute__((ext_vector_type(4)));
typedef unsigned int u32;
typedef u32 __attribute__((address_space(1))) gu32;
typedef u32 __attribute__((address_space(3))) lu32;

__device__ __forceinline__ void gload_lds16(const void* g, void* l) {
    __builtin_amdgcn_global_load_lds((const gu32*)g, (lu32*)l, 16, 0, 0);
}

// ---------------- Kernel 1: LayerNorm + x_norm(bf16) + per-block tile-sum partials
// 512 blocks x 16 rows each (4 rows/wave). partial: [512][2048] f32.
__global__ __launch_bounds__(256) void k_ln(const float* __restrict__ x,
        const float* __restrict__ gamma, const float* __restrict__ beta,
        bf16_t* __restrict__ xn, float* __restrict__ partial)
{
    __shared__ float wsum[4][2048];
    const int tid = threadIdx.x, lane = tid & 63, w = tid >> 6;
    const int blk = blockIdx.x;
    float cs[8][4];
#pragma unroll
    for (int j = 0; j < 8; ++j) { cs[j][0]=0.f; cs[j][1]=0.f; cs[j][2]=0.f; cs[j][3]=0.f; }
#pragma unroll
    for (int i = 0; i < 4; ++i) {
        const int r = blk*16 + w*4 + i;
        const float4* xr = (const float4*)(x + (size_t)r * D_DIM);
        float4 v[8]; float s = 0.f, ss = 0.f;
#pragma unroll
        for (int j = 0; j < 8; ++j) {
            v[j] = xr[j*64 + lane];
            s  += v[j].x + v[j].y + v[j].z + v[j].w;
            ss += v[j].x*v[j].x + v[j].y*v[j].y + v[j].z*v[j].z + v[j].w*v[j].w;
        }
#pragma unroll
        for (int off = 32; off; off >>= 1) { s += __shfl_xor(s, off); ss += __shfl_xor(ss, off); }
        const float mean = s * (1.f/2048.f);
        const float var  = ss * (1.f/2048.f) - mean*mean;
        const float rstd = rsqrtf(var + 1e-5f);
#pragma unroll
        for (int j = 0; j < 8; ++j) {
            const int c4 = j*64 + lane;
            const float4 g4 = *(const float4*)(gamma + c4*4);
            const float4 b4 = *(const float4*)(beta  + c4*4);
            float n0 = (v[j].x - mean)*rstd*g4.x + b4.x;
            float n1 = (v[j].y - mean)*rstd*g4.y + b4.y;
            float n2 = (v[j].z - mean)*rstd*g4.z + b4.z;
            float n3 = (v[j].w - mean)*rstd*g4.w + b4.w;
            cs[j][0]+=n0; cs[j][1]+=n1; cs[j][2]+=n2; cs[j][3]+=n3;
            bf16x4 o; o[0]=(bf16_t)n0; o[1]=(bf16_t)n1; o[2]=(bf16_t)n2; o[3]=(bf16_t)n3;
            *(bf16x4*)(xn + (size_t)r*D_DIM + c4*4) = o;
        }
    }
#pragma unroll
    for (int j = 0; j < 8; ++j) {
        float4 t4; t4.x=cs[j][0]; t4.y=cs[j][1]; t4.z=cs[j][2]; t4.w=cs[j][3];
        *(float4*)&wsum[w][(j*64+lane)*4] = t4;
    }
    __syncthreads();
#pragma unroll
    for (int p = 0; p < 2; ++p) {
        const int c4 = p*256 + tid;  // 0..511 (float4 index)
        float4 a0 = *(const float4*)&wsum[0][c4*4];
        float4 a1 = *(const float4*)&wsum[1][c4*4];
        float4 a2 = *(const float4*)&wsum[2][c4*4];
        float4 a3 = *(const float4*)&wsum[3][c4*4];
        float4 r4; r4.x=a0.x+a1.x+a2.x+a3.x; r4.y=a0.y+a1.y+a2.y+a3.y;
        r4.z=a0.z+a1.z+a2.z+a3.z; r4.w=a0.w+a1.w+a2.w+a3.w;
        *(float4*)(partial + (size_t)blk*D_DIM + c4*4) = r4;
    }
}

// ---------------- Kernel 2a: partial[512][2048] -> partial2[64][2048]
__global__ __launch_bounds__(256) void k_red1(const float* __restrict__ partial,
                                              float* __restrict__ partial2) {
    const int g = blockIdx.x, tid = threadIdx.x;   // 64 blocks
#pragma unroll
    for (int p = 0; p < 2; ++p) {
        const int c4 = p*256 + tid;
        float4 s = {0.f,0.f,0.f,0.f};
#pragma unroll
        for (int r = 0; r < 8; ++r) {
            float4 v = *(const float4*)(partial + ((size_t)(g*8+r))*2048 + c4*4);
            s.x+=v.x; s.y+=v.y; s.z+=v.z; s.w+=v.w;
        }
        *(float4*)(partial2 + (size_t)g*2048 + c4*4) = s;
    }
}

// ---------------- Kernel 3a: reduce partial2 + q/k projection + l2norm
// -> qkbuf[2(which)][2][16][128].  64 blocks: one per (b, t, which).
__global__ __launch_bounds__(256) void k_qk(const float* __restrict__ partial2,
        const float* __restrict__ Wq, const float* __restrict__ bq,
        const float* __restrict__ Wk, const float* __restrict__ bk,
        float* __restrict__ qkbuf)
{
    __shared__ float red2[2][128];
    __shared__ float rrow[128];
    __shared__ float yrow[128];
    __shared__ float ssum[2];
    const int g = blockIdx.x;
    const int b = g >> 5, t = (g >> 1) & 15, which = g & 1;
    const float* W    = which ? Wk : Wq;
    const float* bias = which ? bk : bq;
    const int tid = threadIdx.x, lane = tid & 63, w = tid >> 6;
    // fold of old k_red2: rrow[c] = (sum over 32 partial2 rows)/4096
    {
        const int c = tid & 127, hh = tid >> 7;
        float s = 0.f;
#pragma unroll
        for (int r = 0; r < 16; ++r)
            s += partial2[(size_t)(b*32 + hh*16 + r)*2048 + t*128 + c];
        red2[hh][c] = s;
    }
    __syncthreads();
    if (tid < 128) rrow[tid] = (red2[0][tid] + red2[1][tid]) * (1.f/4096.f);
    __syncthreads();
    const int c0 = (lane & 15) * 8;
#pragma unroll
    for (int r = 0; r < 8; ++r) {
        const int d = r*16 + w*4 + (lane >> 4);   // covers 0..127
        const float4 w0 = *(const float4*)(W + d*128 + c0);
        const float4 w1 = *(const float4*)(W + d*128 + c0 + 4);
        float acc = w0.x*rrow[c0]   + w0.y*rrow[c0+1] + w0.z*rrow[c0+2] + w0.w*rrow[c0+3]
                  + w1.x*rrow[c0+4] + w1.y*rrow[c0+5] + w1.z*rrow[c0+6] + w1.w*rrow[c0+7];
#pragma unroll
        for (int off = 1; off <= 8; off <<= 1) acc += __shfl_xor(acc, off);
        if ((lane & 15) == 0) yrow[d] = acc + bias[d];
    }
    __syncthreads();
    if (tid < 128) {
        float v = yrow[tid];
        float sq = v * v;
#pragma unroll
        for (int off = 32; off; off >>= 1) sq += __shfl_xor(sq, off);
        if (lane == 0) ssum[tid >> 6] = sq;
    }
    __syncthreads();
    if (tid < 128) {
        const float rn = 1.f / fmaxf(sqrtf(ssum[0] + ssum[1]), 1e-12f);
        qkbuf[(which*32 + b*16 + t)*128 + tid] = yrow[tid] * rn;
    }
}

// ---------------- Kernel 3b: scores + top-4 -> routes [B][T][K]
__global__ __launch_bounds__(256) void k_score(const float* __restrict__ qkbuf,
                                               int* __restrict__ routes)
{
    __shared__ float qk_s[8192];      // [which(2)][b(2)][t(16)][128]
    __shared__ float sc[2][16][16];
    const int tid = threadIdx.x;
    for (int i = tid; i < 2048; i += 256)
        *(float4*)&qk_s[i*4] = *(const float4*)(qkbuf + i*4);
    __syncthreads();
#pragma unroll
    for (int p = 0; p < 2; ++p) {
        const int e = p*256 + tid;            // 0..511
        const int b = e >> 8, t = (e >> 4) & 15, u = e & 15;
        const float4* qr = (const float4*)&qk_s[(b*16 + t)*128];
        const float4* kr = (const float4*)&qk_s[(32 + b*16 + u)*128];
        float s = 0.f;
#pragma unroll
        for (int c = 0; c < 32; ++c) {
            float4 a = qr[c], bb = kr[c];
            s += a.x*bb.x + a.y*bb.y + a.z*bb.z + a.w*bb.w;
        }
        sc[b][t][u] = (u == t) ? -1e9f : s;
    }
    __syncthreads();
    if (tid < 32) {
        const int b = tid >> 4, t = tid & 15;
        unsigned taken = 0;
        for (int kk = 0; kk < 4; ++kk) {
            float bv = -3.0e38f; int bu = 0;
            for (int u = 0; u < 16; ++u) {
                if ((taken >> u) & 1u) continue;
                const float v = sc[b][t][u];
                if (v > bv) { bv = v; bu = u; }   // strict > = lax.top_k tie-break
            }
            taken |= (1u << bu);
            routes[(b*16 + t)*4 + kk] = bu;
        }
    }
}

// ---------------- Kernel 4: pre-tile + pre-swizzle W1/W2 into bf16 LDS images
// LDS slot L holds logical element at (byte L) ^ ((row&7)<<4)  [rows of 128B]
__global__ void k_prep(const float* __restrict__ W1, const float* __restrict__ W2,
                       bf16_t* __restrict__ W1t, bf16_t* __restrict__ W2t) {
    const int g = blockIdx.x * 256 + threadIdx.x;
    if (g < 10*256*64) {
        const int ks = g >> 14, rem = g & 16383, n = rem >> 6, kk = rem & 63;
        const int kkl = ((kk << 1) ^ ((n & 7) << 4)) >> 1;
        W1t[g] = (bf16_t)W1[n*CTX + ks*64 + kkl];
    } else if (g < 10*256*64 + 4*128*64) {
        const int gg = g - 10*256*64;
        const int ks = gg >> 13, rem = gg & 8191, n = rem >> 6, kk = rem & 63;
        const int kkl = ((kk << 1) ^ ((n & 7) << 4)) >> 1;
        W2t[gg] = (bf16_t)W2[n*HID + ks*64 + kkl];
    }
}

// ---------------- Kernel 5: fused gather + MLP, 256-row deep-pipelined version.
// 512 blocks x 512 threads (8 waves). BM=256 rows (16 s x 16 t), BN=256 (GEMM1).
// Wave (wr=w>>2, wc=w&3): GEMM1 output 128m x 64n, acc[4][8].
// LDS (128KB, 1 block/CU): A-dbuf [0,64K), W1-dbuf [64K,128K);
// after GEMM1: hA [256][128] 64KB @0, W2 (all 4 subtiles) 64KB @64K; srcT @96K (transient).
// K-loop: stage(ks+1) at step bottom; counted s_waitcnt vmcnt(8) at step top (T3/T4);
// setprio around MFMA cluster (T5). NO min-waves in launch_bounds (round-5 lesson).
__global__ __launch_bounds__(512, 1) void k_mlp(
    const float* __restrict__ x, const bf16_t* __restrict__ xn,
    const bf16_t* __restrict__ W1t, const bf16_t* __restrict__ W2t,
    const float* __restrict__ b1, const float* __restrict__ b2,
    const int* __restrict__ routes, float* __restrict__ out)
{
    __shared__ char lds[131072];
    int* srcT = (int*)(lds + 98304);   // transient: dead before any staging lands there

    const int tid = threadIdx.x, lane = tid & 63, w = tid >> 6;
    const int blk = blockIdx.x;
    const int b  = blk >> 8;
    const int s0 = (blk & 255) * 16;

    if (tid < 80) {
        const int t = tid / 5, j = tid % 5;
        srcT[tid] = (j == 0) ? t : routes[(b*NT + t)*KW + (j-1)];
    }
    __syncthreads();

    // staging-lane constants: chunk q=it*8+w covers m-rows q*8..q*8+7 (m = it*64 + u)
    const int u  = w*8 + (lane >> 3);           // 0..63
    const int tt = u & 15;                      // tile index t of this lane's m-rows
    const int hi = u >> 4;                      // 0..3
    const size_t rowbase = ((size_t)(b*S_LEN + s0 + hi)) * D_DIM;
    const int kkE = ((lane & 7) ^ ((lane >> 3) & 7)) * 8;  // source-side swizzle

    int r_src[5];
#pragma unroll
    for (int j = 0; j < 5; ++j) r_src[j] = srcT[tt*5 + j];
    __syncthreads();   // all srcT reads retired before any LDS region reuse

    const int wc = w & 3, wr = w >> 2;
    const int nbase = wc * 64;

    f32x4 acc[4][8];
#pragma unroll
    for (int i = 0; i < 4; ++i)
#pragma unroll
        for (int j = 0; j < 8; ++j) acc[i][j] = (f32x4){0.f,0.f,0.f,0.f};

    auto STAGE = [&](int ksv) {
        const int buf  = (ksv & 1) * 32768;
        const int half = (ksv & 1) * 64;
        const size_t gb = rowbase + (size_t)r_src[ksv >> 1]*TD + (size_t)(half + kkE);
#pragma unroll
        for (int it = 0; it < 4; ++it)
            gload_lds16(xn + gb + (size_t)(it*4)*D_DIM, lds + buf + (it*8 + w)*1024);
        const bf16_t* w1g = W1t + ksv*16384 + lane*8;
#pragma unroll
        for (int it = 0; it < 4; ++it)
            gload_lds16(w1g + (it*8 + w)*512, lds + 65536 + buf + (it*8 + w)*1024);
    };

    STAGE(0);
    STAGE(1);

    for (int ks = 0; ks < 10; ++ks) {
        if (ks < 9) asm volatile("s_waitcnt vmcnt(8)" ::: "memory");
        else        asm volatile("s_waitcnt vmcnt(0)" ::: "memory");
        __builtin_amdgcn_s_barrier();
        __builtin_amdgcn_sched_barrier(0);
        const char* cA = lds + (ks & 1) * 32768;
        const char* cB = lds + 65536 + (ks & 1) * 32768;
        __builtin_amdgcn_s_setprio(1);
#pragma unroll
        for (int kk = 0; kk < 2; ++kk) {
            const int kb = (kk*32 + ((lane >> 4) * 8)) * 2;
            bf16x8 af[4], bfr[8];
#pragma unroll
            for (int nf = 0; nf < 4; ++nf) {
                const int n = nbase + nf*16 + (lane & 15);
                af[nf] = *(const bf16x8*)(cB + n*128 + (kb ^ ((n & 7) << 4)));
            }
#pragma unroll
            for (int mf = 0; mf < 8; ++mf) {
                const int m = wr*128 + mf*16 + (lane & 15);
                bfr[mf] = *(const bf16x8*)(cA + m*128 + (kb ^ ((m & 7) << 4)));
            }
#pragma unroll
            for (int nf = 0; nf < 4; ++nf)
#pragma unroll
                for (int mf = 0; mf < 8; ++mf)
                    acc[nf][mf] = __builtin_amdgcn_mfma_f32_16x16x32_bf16(
                        af[nf], bfr[mf], acc[nf][mf], 0, 0, 0);
        }
        __builtin_amdgcn_s_setprio(0);
        asm volatile("s_waitcnt lgkmcnt(0)" ::: "memory");
        __builtin_amdgcn_s_barrier();
        if (ks < 8) STAGE(ks + 2);
    }

    // epilogue 1: bias + gelu (tanh approx) -> packed bf16 regs
    bf16x4 hreg[4][8];
#pragma unroll
    for (int nf = 0; nf < 4; ++nf) {
        const int k0 = nbase + nf*16 + ((lane >> 4) * 4);
        const float4 b1v = *(const float4*)(b1 + k0);
#pragma unroll
        for (int mf = 0; mf < 8; ++mf) {
#pragma unroll
            for (int r = 0; r < 4; ++r) {
                const float z = acc[nf][mf][r] + ((const float*)&b1v)[r];
                const float uu = z + 0.044715f * z * z * z;
                const float gl = z / (1.f + __expf(-1.5957691216f * uu));
                hreg[nf][mf][r] = (bf16_t)gl;
            }
        }
    }

    // stage ALL of W2 (64KB) into [64K,128K) — W1-dbuf dead after GEMM1
#pragma unroll
    for (int it = 0; it < 8; ++it) {
        const int q = it*8 + w;
        gload_lds16(W2t + q*512 + lane*8, lds + 65536 + q*1024);
    }

    char* hA = lds;  // [256 m][128 k] bf16, 64KB, row stride 256B (phased over k-halves)

    // phase A: waves wc<2 write h cols 0..127
    if (wc < 2) {
#pragma unroll
        for (int nf = 0; nf < 4; ++nf) {
            const int kA2 = (nbase + nf*16 + ((lane >> 4) * 4)) * 2;   // nbase in {0,64}
#pragma unroll
            for (int mf = 0; mf < 8; ++mf) {
                const int m = wr*128 + mf*16 + (lane & 15);
                *(bf16x4*)(hA + m*256 + (kA2 ^ ((m & 7) << 4))) = hreg[nf][mf];
            }
        }
    }
    asm volatile("s_waitcnt vmcnt(0)" ::: "memory");
    __syncthreads();

    // GEMM2: out = h @ W2^T, M=256 (wm=w>>1), N=128 (wn=w&1), K=256 in 2 phases
    const int wn = w & 1, wm = w >> 1;
    const int n2b = wn*64, m2b = wm*64;
    f32x4 acc2[4][4];
#pragma unroll
    for (int i = 0; i < 4; ++i)
#pragma unroll
        for (int j = 0; j < 4; ++j) acc2[i][j] = (f32x4){0.f,0.f,0.f,0.f};

#pragma unroll
    for (int kph = 0; kph < 2; ++kph) {
        if (kph == 1) {
            __syncthreads();   // phase-A h reads done
            if (wc >= 2) {     // phase B: waves wc>=2 write h cols 128..255
#pragma unroll
                for (int nf = 0; nf < 4; ++nf) {
                    const int kA2 = ((nbase - 128) + nf*16 + ((lane >> 4) * 4)) * 2;
#pragma unroll
                    for (int mf = 0; mf < 8; ++mf) {
                        const int m = wr*128 + mf*16 + (lane & 15);
                        *(bf16x4*)(hA + m*256 + (kA2 ^ ((m & 7) << 4))) = hreg[nf][mf];
                    }
                }
            }
            __syncthreads();
        }
#pragma unroll
        for (int ksl = 0; ksl < 2; ++ksl) {
#pragma unroll
            for (int kk = 0; kk < 2; ++kk) {
                const int kbH = (ksl*64 + kk*32 + ((lane >> 4) * 8)) * 2;
                const int kbW = (kk*32 + ((lane >> 4) * 8)) * 2;
                bf16x8 ah[4], bw[4];
#pragma unroll
                for (int mf2 = 0; mf2 < 4; ++mf2) {
                    const int m = m2b + mf2*16 + (lane & 15);
                    ah[mf2] = *(const bf16x8*)(hA + m*256 + (kbH ^ ((m & 7) << 4)));
                }
#pragma unroll
                for (int nf2 = 0; nf2 < 4; ++nf2) {
                    const int n = n2b + nf2*16 + (lane & 15);
                    bw[nf2] = *(const bf16x8*)(lds + 65536 + (kph*2 + ksl)*16384
                                               + n*128 + (kbW ^ ((n & 7) << 4)));
                }
#pragma unroll
                for (int nf2 = 0; nf2 < 4; ++nf2)
#pragma unroll
                    for (int mf2 = 0; mf2 < 4; ++mf2)
                        acc2[nf2][mf2] = __builtin_amdgcn_mfma_f32_16x16x32_bf16(
                            ah[mf2], bw[nf2], acc2[nf2][mf2], 0, 0, 0);
            }
        }
    }

    // epilogue 2: + b2 + residual x
#pragma unroll
    for (int nf2 = 0; nf2 < 4; ++nf2) {
        const int n2 = n2b + nf2*16 + (lane & 15);
        const float b2v = b2[n2];
#pragma unroll
        for (int mf2 = 0; mf2 < 4; ++mf2) {
            const int mb = m2b + mf2*16 + ((lane >> 4) * 4);
#pragma unroll
            for (int r = 0; r < 4; ++r) {
                const int m = mb + r;
                const int s = s0 + (m >> 4);
                const int t = m & 15;
                const size_t o = ((size_t)(b*S_LEN + s))*D_DIM + t*TD + n2;
                out[o] = x[o] + acc2[nf2][mf2][r] + b2v;
            }
        }
    }
}

extern "C" void kernel_launch(void* const* d_in, const int* in_sizes, int n_in,
                              void* d_out, int out_size, void* d_ws, size_t ws_size,
                              hipStream_t stream) {
    const float* x     = (const float*)d_in[0];
    const float* gamma = (const float*)d_in[1];
    const float* beta  = (const float*)d_in[2];
    const float* Wq    = (const float*)d_in[3];
    const float* bq    = (const float*)d_in[4];
    const float* Wk    = (const float*)d_in[5];
    const float* bk    = (const float*)d_in[6];
    const float* W1    = (const float*)d_in[7];
    const float* b1    = (const float*)d_in[8];
    const float* W2    = (const float*)d_in[9];
    const float* b2    = (const float*)d_in[10];
    float* out = (float*)d_out;

    char* ws = (char*)d_ws;
    bf16_t* xn       = (bf16_t*)ws;                   // 33,554,432 B
    float*  partial  = (float*) (ws + 33554432);      //  4,194,304 B [512][2048]
    float*  partial2 = (float*) (ws + 37748736);      //    524,288 B [64][2048]
    float*  qkbuf    = (float*) (ws + 38273024);      //     32,768 B
    int*    routes   = (int*)   (ws + 38305792);      //        512 B
    bf16_t* W1t      = (bf16_t*)(ws + 38306304);      //    327,680 B
    bf16_t* W2t      = (bf16_t*)(ws + 38633984);      //     65,536 B

    k_prep<<<768, 256, 0, stream>>>(W1, W2, W1t, W2t);
    k_ln<<<512, 256, 0, stream>>>(x, gamma, beta, xn, partial);
    k_red1<<<64, 256, 0, stream>>>(partial, partial2);
    k_qk<<<64, 256, 0, stream>>>(partial2, Wq, bq, Wk, bk, qkbuf);
    k_score<<<1, 256, 0, stream>>>(qkbuf, routes);
    k_mlp<<<512, 512, 0, stream>>>(x, xn, W1t, W2t, b1, b2, routes, out);
}